// Round 1
// baseline (329.093 us; speedup 1.0000x reference)
//
#include <hip/hip_runtime.h>
#include <hip/hip_bf16.h>

// Problem constants
#define Bb 256
#define Tt 128
#define Nn 512
#define Hh 128
// 4H = 512

typedef __attribute__((ext_vector_type(4))) float floatx4;
typedef __attribute__((ext_vector_type(8))) short short8;

__device__ __forceinline__ unsigned short f2bf(float f) {
  unsigned u = __float_as_uint(f);
  u += 0x7fffu + ((u >> 16) & 1u);   // round-to-nearest-even
  return (unsigned short)(u >> 16);
}

// ---------------------------------------------------------------------------
// Kernel 1: convert w_ih to bf16, precompute bias = b_ih + b_hh
// ---------------------------------------------------------------------------
__global__ void prep_kernel(const float* __restrict__ w_ih,
                            const float* __restrict__ b_ih,
                            const float* __restrict__ b_hh,
                            unsigned short* __restrict__ wb,
                            float* __restrict__ bias) {
  int i = blockIdx.x * 256 + threadIdx.x;
  if (i < 4 * Hh * Nn) wb[i] = f2bf(w_ih[i]);
  if (i < 4 * Hh) bias[i] = b_ih[i] + b_hh[i];
}

// ---------------------------------------------------------------------------
// Kernel 2: alpha[b,n] = softmax_n( sum_t X[b,t,n] * w_x[t] )
// (softmax shift-invariance kills the h/c-dependent scalar term)
// ---------------------------------------------------------------------------
__global__ __launch_bounds__(512) void alpha_kernel(const float* __restrict__ X,
                                                    const float* __restrict__ attn_w,
                                                    float* __restrict__ alpha) {
  int b = blockIdx.x;
  int n = threadIdx.x;                     // 512 threads
  const float* Xb = X + (size_t)b * Tt * Nn + n;
  float acc = 0.f;
#pragma unroll 8
  for (int t = 0; t < Tt; ++t)
    acc = fmaf(Xb[(size_t)t * Nn], attn_w[2 * Hh + t], acc);

  __shared__ float red[512];
  red[n] = acc;
  __syncthreads();
  for (int s = 256; s > 0; s >>= 1) {
    if (n < s) red[n] = fmaxf(red[n], red[n + s]);
    __syncthreads();
  }
  float m = red[0];
  __syncthreads();
  float e = __expf(acc - m);
  red[n] = e;
  __syncthreads();
  for (int s = 256; s > 0; s >>= 1) {
    if (n < s) red[n] += red[n + s];
    __syncthreads();
  }
  alpha[(size_t)b * Nn + n] = e / red[0];
}

// ---------------------------------------------------------------------------
// Kernel 3: Xt = alpha * X (fp32, output 0) and xtb = bf16(Xt) for the GEMM
// ---------------------------------------------------------------------------
__global__ __launch_bounds__(256) void scale_kernel(const float* __restrict__ X,
                                                    const float* __restrict__ alpha,
                                                    float* __restrict__ Xt,
                                                    unsigned short* __restrict__ xtb) {
  size_t i = (size_t)blockIdx.x * 256 + threadIdx.x;  // float4 index; grid is exact
  size_t e = i * 4;
  int n = (int)(e & (Nn - 1));
  int brow = (int)(e >> 9);   // b*T + t
  int b = brow >> 7;          // T = 128
  float4 x = ((const float4*)X)[i];
  float4 a = *(const float4*)(alpha + (size_t)b * Nn + n);
  float4 y;
  y.x = x.x * a.x; y.y = x.y * a.y; y.z = x.z * a.z; y.w = x.w * a.w;
  ((float4*)Xt)[i] = y;
  ushort4 u;
  u.x = f2bf(y.x); u.y = f2bf(y.y); u.z = f2bf(y.z); u.w = f2bf(y.w);
  ((ushort4*)xtb)[i] = u;
}

// ---------------------------------------------------------------------------
// Kernel 4: G[m, j] = sum_k xtb[m,k] * w_ih[j,k] + bias[j]   (bf16 MFMA)
// M = B*T = 32768, N = 512, K = 512. B^T layout (w_ih rows are k-contiguous).
// 128x128 block tile, 4 waves in 2x2, each wave 64x64 via 4x4 frags 16x16x32.
// ---------------------------------------------------------------------------
#define GBK 64
#define LDK 72  // GBK + 8 bf16 pad -> 144B row stride, 2-way-max bank aliasing

__global__ __launch_bounds__(256) void gemm_bt(const unsigned short* __restrict__ A,
                                               const unsigned short* __restrict__ Bw,
                                               const float* __restrict__ bias,
                                               float* __restrict__ C) {
  __shared__ __align__(16) unsigned short As[128 * LDK];
  __shared__ __align__(16) unsigned short Bs[128 * LDK];
  const int K = 512, NO = 512;
  int tid = threadIdx.x;
  int lane = tid & 63;
  int wave = tid >> 6;
  int wm = wave & 1, wn = wave >> 1;
  int l15 = lane & 15;
  int quad = lane >> 4;
  int mtile = blockIdx.x, ntile = blockIdx.y;

  floatx4 acc[4][4];
#pragma unroll
  for (int i = 0; i < 4; ++i)
#pragma unroll
    for (int j = 0; j < 4; ++j) acc[i][j] = (floatx4){0.f, 0.f, 0.f, 0.f};

  const size_t abase = (size_t)mtile * 128 * K;
  const size_t bbase = (size_t)ntile * 128 * K;

  for (int kb = 0; kb < K; kb += GBK) {
    // stage 128x64 bf16 tiles of A and B^T; 16B per thread per slot
#pragma unroll
    for (int s = 0; s < 4; ++s) {
      int idx = s * 256 + tid;       // 0..1023
      int r = idx >> 3;
      int c = (idx & 7) * 8;
      uint4 va = *(const uint4*)(A + abase + (size_t)r * K + kb + c);
      *(uint4*)(&As[r * LDK + c]) = va;
      uint4 vb = *(const uint4*)(Bw + bbase + (size_t)r * K + kb + c);
      *(uint4*)(&Bs[r * LDK + c]) = vb;
    }
    __syncthreads();
#pragma unroll
    for (int ks = 0; ks < GBK; ks += 32) {
      int kof = ks + quad * 8;
      short8 af[4], bf[4];
#pragma unroll
      for (int i = 0; i < 4; ++i)
        af[i] = *(const short8*)(&As[(wm * 64 + i * 16 + l15) * LDK + kof]);
#pragma unroll
      for (int j = 0; j < 4; ++j)
        bf[j] = *(const short8*)(&Bs[(wn * 64 + j * 16 + l15) * LDK + kof]);
#pragma unroll
      for (int i = 0; i < 4; ++i)
#pragma unroll
        for (int j = 0; j < 4; ++j)
          acc[i][j] = __builtin_amdgcn_mfma_f32_16x16x32_bf16(af[i], bf[j], acc[i][j], 0, 0, 0);
    }
    __syncthreads();
  }

  // Epilogue: C/D mapping col = lane&15 (n), row = quad*4 + reg (m)
  int m0 = mtile * 128 + wm * 64;
  int n0 = ntile * 128 + wn * 64;
#pragma unroll
  for (int j = 0; j < 4; ++j) {
    int col = n0 + j * 16 + l15;
    float bsum = bias[col];
#pragma unroll
    for (int i = 0; i < 4; ++i) {
      int row = m0 + i * 16 + quad * 4;
#pragma unroll
      for (int r = 0; r < 4; ++r)
        C[(size_t)(row + r) * NO + col] = acc[i][j][r] + bsum;
    }
  }
}

// ---------------------------------------------------------------------------
// Kernel 5: sequential LSTM over T. One block per batch; thread j owns gate j
// (w_hh row j in 128 VGPRs). h broadcast from LDS; c lives in regs of j<128.
// ---------------------------------------------------------------------------
__global__ __launch_bounds__(512) void lstm_kernel(const float* __restrict__ G,
                                                   const float* __restrict__ w_hh,
                                                   float* __restrict__ Xe) {
  int b = blockIdx.x;
  int j = threadIdx.x;   // 512

  float w[128];
#pragma unroll
  for (int k = 0; k < 128; k += 4) {
    float4 v = *(const float4*)(w_hh + (size_t)j * 128 + k);
    w[k] = v.x; w[k + 1] = v.y; w[k + 2] = v.z; w[k + 3] = v.w;
  }

  __shared__ float h_sh[128];
  __shared__ float gates_sh[512];
  float c_reg = 0.f;
  if (j < Hh) h_sh[j] = 0.f;
  __syncthreads();

  const float* Gb = G + (size_t)b * Tt * 512 + j;
  float* Xeb = Xe + (size_t)b * Tt * Hh;

  float gnext = Gb[0];
  for (int t = 0; t < Tt; ++t) {
    float acc = gnext;
    if (t + 1 < Tt) gnext = Gb[(size_t)(t + 1) * 512];   // prefetch next step's G
#pragma unroll
    for (int k = 0; k < 128; k += 4) {
      float4 h4 = *(const float4*)(&h_sh[k]);            // 64-lane broadcast read
      acc = fmaf(w[k],     h4.x, acc);
      acc = fmaf(w[k + 1], h4.y, acc);
      acc = fmaf(w[k + 2], h4.z, acc);
      acc = fmaf(w[k + 3], h4.w, acc);
    }
    gates_sh[j] = acc;
    __syncthreads();
    if (j < Hh) {
      float ig = gates_sh[j];
      float fg = gates_sh[Hh + j];
      float gg = gates_sh[2 * Hh + j];
      float og = gates_sh[3 * Hh + j];
      float si = 1.f / (1.f + __expf(-ig));
      float sf = 1.f / (1.f + __expf(-fg));
      float so = 1.f / (1.f + __expf(-og));
      float tg = tanhf(gg);
      c_reg = sf * c_reg + si * tg;
      float hn = so * tanhf(c_reg);
      h_sh[j] = hn;
      Xeb[(size_t)t * Hh + j] = hn;
    }
    __syncthreads();
  }
}

// ---------------------------------------------------------------------------
extern "C" void kernel_launch(void* const* d_in, const int* in_sizes, int n_in,
                              void* d_out, int out_size, void* d_ws, size_t ws_size,
                              hipStream_t stream) {
  const float* X      = (const float*)d_in[0];
  const float* attn_w = (const float*)d_in[1];
  // d_in[2] = attn_b: cancels in softmax, unused
  const float* w_ih   = (const float*)d_in[3];
  const float* w_hh   = (const float*)d_in[4];
  const float* b_ih   = (const float*)d_in[5];
  const float* b_hh   = (const float*)d_in[6];

  float* Xt = (float*)d_out;                                  // (B,T,N)
  float* Xe = (float*)d_out + (size_t)Bb * Tt * Nn;           // (B,T,H)

  char* ws = (char*)d_ws;
  float*          alpha = (float*)(ws);                        //   512 KB
  float*          bias  = (float*)(ws + 524288);               //     2 KB
  unsigned short* wb    = (unsigned short*)(ws + 526336);      //   512 KB
  unsigned short* xtb   = (unsigned short*)(ws + 1050624);     //    32 MB
  float*          G     = (float*)(ws + 34605056);             //    64 MB
  // total ws use ~97 MB

  prep_kernel<<<dim3(1024), dim3(256), 0, stream>>>(w_ih, b_ih, b_hh, wb, bias);
  alpha_kernel<<<dim3(Bb), dim3(512), 0, stream>>>(X, attn_w, alpha);
  scale_kernel<<<dim3(16384), dim3(256), 0, stream>>>(X, alpha, Xt, xtb);
  gemm_bt<<<dim3(256, 4), dim3(256), 0, stream>>>(xtb, wb, bias, G);
  lstm_kernel<<<dim3(Bb), dim3(512), 0, stream>>>(G, w_hh, Xe);
}

// Round 2
// 324.016 us; speedup vs baseline: 1.0157x; 1.0157x over previous
//
#include <hip/hip_runtime.h>
#include <hip/hip_bf16.h>

// Problem constants
#define Bb 256
#define Tt 128
#define Nn 512
#define Hh 128
// 4H = 512

typedef __attribute__((ext_vector_type(4))) float floatx4;
typedef __attribute__((ext_vector_type(8))) short short8;

__device__ __forceinline__ unsigned short f2bf(float f) {
  unsigned u = __float_as_uint(f);
  u += 0x7fffu + ((u >> 16) & 1u);   // round-to-nearest-even
  return (unsigned short)(u >> 16);
}

__device__ __forceinline__ float sigmoid_fast(float x) {
  return 1.f / (1.f + __expf(-x));
}
__device__ __forceinline__ float tanh_fast(float x) {
  float e = __expf(2.f * x);
  return 1.f - 2.f / (e + 1.f);   // safe: e=inf -> 1, e=0 -> -1
}

// ---------------------------------------------------------------------------
// Kernel 1: convert w_ih to bf16, precompute bias = b_ih + b_hh
// ---------------------------------------------------------------------------
__global__ void prep_kernel(const float* __restrict__ w_ih,
                            const float* __restrict__ b_ih,
                            const float* __restrict__ b_hh,
                            unsigned short* __restrict__ wb,
                            float* __restrict__ bias) {
  int i = blockIdx.x * 256 + threadIdx.x;
  if (i < 4 * Hh * Nn) wb[i] = f2bf(w_ih[i]);
  if (i < 4 * Hh) bias[i] = b_ih[i] + b_hh[i];
}

// ---------------------------------------------------------------------------
// Kernel 2: alpha[b,n] = softmax_n( sum_t X[b,t,n] * w_x[t] )
// (softmax shift-invariance kills the h/c-dependent scalar term)
// ---------------------------------------------------------------------------
__global__ __launch_bounds__(512) void alpha_kernel(const float* __restrict__ X,
                                                    const float* __restrict__ attn_w,
                                                    float* __restrict__ alpha) {
  int b = blockIdx.x;
  int n = threadIdx.x;                     // 512 threads
  const float* Xb = X + (size_t)b * Tt * Nn + n;
  float acc = 0.f;
#pragma unroll 8
  for (int t = 0; t < Tt; ++t)
    acc = fmaf(Xb[(size_t)t * Nn], attn_w[2 * Hh + t], acc);

  __shared__ float red[512];
  red[n] = acc;
  __syncthreads();
  for (int s = 256; s > 0; s >>= 1) {
    if (n < s) red[n] = fmaxf(red[n], red[n + s]);
    __syncthreads();
  }
  float m = red[0];
  __syncthreads();
  float e = __expf(acc - m);
  red[n] = e;
  __syncthreads();
  for (int s = 256; s > 0; s >>= 1) {
    if (n < s) red[n] += red[n + s];
    __syncthreads();
  }
  alpha[(size_t)b * Nn + n] = e / red[0];
}

// ---------------------------------------------------------------------------
// Kernel 3: Xt = alpha * X (fp32, output 0) and xtb = bf16(Xt) for the GEMM
// ---------------------------------------------------------------------------
__global__ __launch_bounds__(256) void scale_kernel(const float* __restrict__ X,
                                                    const float* __restrict__ alpha,
                                                    float* __restrict__ Xt,
                                                    unsigned short* __restrict__ xtb) {
  size_t i = (size_t)blockIdx.x * 256 + threadIdx.x;  // float4 index; grid is exact
  size_t e = i * 4;
  int n = (int)(e & (Nn - 1));
  int brow = (int)(e >> 9);   // b*T + t
  int b = brow >> 7;          // T = 128
  float4 x = ((const float4*)X)[i];
  float4 a = *(const float4*)(alpha + (size_t)b * Nn + n);
  float4 y;
  y.x = x.x * a.x; y.y = x.y * a.y; y.z = x.z * a.z; y.w = x.w * a.w;
  ((float4*)Xt)[i] = y;
  ushort4 u;
  u.x = f2bf(y.x); u.y = f2bf(y.y); u.z = f2bf(y.z); u.w = f2bf(y.w);
  ((ushort4*)xtb)[i] = u;
}

// ---------------------------------------------------------------------------
// Kernel 4: G[m, j] = sum_k xtb[m,k] * w_ih[j,k] + bias[j]   (bf16 MFMA)
// M = B*T = 32768, N = 512, K = 512. B^T layout (w_ih rows are k-contiguous).
// 128x128 block tile, 4 waves in 2x2, each wave 64x64 via 4x4 frags 16x16x32.
// ---------------------------------------------------------------------------
#define GBK 64
#define LDK 72  // GBK + 8 bf16 pad -> 144B row stride, 2-way-max bank aliasing

__global__ __launch_bounds__(256) void gemm_bt(const unsigned short* __restrict__ A,
                                               const unsigned short* __restrict__ Bw,
                                               const float* __restrict__ bias,
                                               float* __restrict__ C) {
  __shared__ __align__(16) unsigned short As[128 * LDK];
  __shared__ __align__(16) unsigned short Bs[128 * LDK];
  const int K = 512, NO = 512;
  int tid = threadIdx.x;
  int lane = tid & 63;
  int wave = tid >> 6;
  int wm = wave & 1, wn = wave >> 1;
  int l15 = lane & 15;
  int quad = lane >> 4;
  int mtile = blockIdx.x, ntile = blockIdx.y;

  floatx4 acc[4][4];
#pragma unroll
  for (int i = 0; i < 4; ++i)
#pragma unroll
    for (int j = 0; j < 4; ++j) acc[i][j] = (floatx4){0.f, 0.f, 0.f, 0.f};

  const size_t abase = (size_t)mtile * 128 * K;
  const size_t bbase = (size_t)ntile * 128 * K;

  for (int kb = 0; kb < K; kb += GBK) {
    // stage 128x64 bf16 tiles of A and B^T; 16B per thread per slot
#pragma unroll
    for (int s = 0; s < 4; ++s) {
      int idx = s * 256 + tid;       // 0..1023
      int r = idx >> 3;
      int c = (idx & 7) * 8;
      uint4 va = *(const uint4*)(A + abase + (size_t)r * K + kb + c);
      *(uint4*)(&As[r * LDK + c]) = va;
      uint4 vb = *(const uint4*)(Bw + bbase + (size_t)r * K + kb + c);
      *(uint4*)(&Bs[r * LDK + c]) = vb;
    }
    __syncthreads();
#pragma unroll
    for (int ks = 0; ks < GBK; ks += 32) {
      int kof = ks + quad * 8;
      short8 af[4], bf[4];
#pragma unroll
      for (int i = 0; i < 4; ++i)
        af[i] = *(const short8*)(&As[(wm * 64 + i * 16 + l15) * LDK + kof]);
#pragma unroll
      for (int j = 0; j < 4; ++j)
        bf[j] = *(const short8*)(&Bs[(wn * 64 + j * 16 + l15) * LDK + kof]);
#pragma unroll
      for (int i = 0; i < 4; ++i)
#pragma unroll
        for (int j = 0; j < 4; ++j)
          acc[i][j] = __builtin_amdgcn_mfma_f32_16x16x32_bf16(af[i], bf[j], acc[i][j], 0, 0, 0);
    }
    __syncthreads();
  }

  // Epilogue: C/D mapping col = lane&15 (n), row = quad*4 + reg (m)
  int m0 = mtile * 128 + wm * 64;
  int n0 = ntile * 128 + wn * 64;
#pragma unroll
  for (int j = 0; j < 4; ++j) {
    int col = n0 + j * 16 + l15;
    float bsum = bias[col];
#pragma unroll
    for (int i = 0; i < 4; ++i) {
      int row = m0 + i * 16 + quad * 4;
#pragma unroll
      for (int r = 0; r < 4; ++r)
        C[(size_t)(row + r) * NO + col] = acc[i][j][r] + bsum;
    }
  }
}

// ---------------------------------------------------------------------------
// Kernel 5: sequential LSTM via M-replicated MFMA.
// One block per batch, 256 threads = 4 waves. Each wave owns 8 n-frags:
//   n(f) = ftype*128 + wave*32 + half*16   (f = ftype*2 + half)
// so i,f,g,o for unit j = wave*32 + half*16 + l15 all live in the SAME lane.
// A-operand: every lane loads the same h[k] slice -> all 16 M-rows identical
// -> acc[f][0] is a valid gate in EVERY lane (quads are natural duplicates).
// G_t enters as the MFMA C-operand (splat), prefetched 2 steps ahead.
// w_hh is preloaded as bf16 B-frags in 128 VGPRs. h: 256B double-buffered LDS.
// ---------------------------------------------------------------------------
__global__ __launch_bounds__(256, 1) void lstm_kernel(const float* __restrict__ G,
                                                      const float* __restrict__ w_hh,
                                                      float* __restrict__ Xe) {
  int b = blockIdx.x;
  int tid = threadIdx.x;
  int w = tid >> 6;
  int lane = tid & 63;
  int l15 = lane & 15;
  int quad = lane >> 4;

  // Preload w_hh^T B-frags (bf16). B-frag layout: n = l15, k = quad*8 + jj
  // (verified empirically by the passing R1 gemm_bt).
  short8 bfr[8][4];
#pragma unroll
  for (int f = 0; f < 8; ++f) {
    int ftype = f >> 1, half = f & 1;
    int n = ftype * 128 + w * 32 + half * 16 + l15;
    const float* src = w_hh + (size_t)n * 128;
#pragma unroll
    for (int kf = 0; kf < 4; ++kf) {
      int k0 = kf * 32 + quad * 8;
      float4 lo = *(const float4*)(src + k0);
      float4 hi = *(const float4*)(src + k0 + 4);
      short8 v;
      v[0] = (short)f2bf(lo.x); v[1] = (short)f2bf(lo.y);
      v[2] = (short)f2bf(lo.z); v[3] = (short)f2bf(lo.w);
      v[4] = (short)f2bf(hi.x); v[5] = (short)f2bf(hi.y);
      v[6] = (short)f2bf(hi.z); v[7] = (short)f2bf(hi.w);
      bfr[f][kf] = v;
    }
  }

  __shared__ __align__(16) unsigned short h_sh[2][128];
  if (tid < 128) h_sh[0][tid] = 0;   // h0 = 0 (bf16 zero)
  __syncthreads();

  const float* Gb = G + (size_t)b * Tt * 512;
  float* Xeb = Xe + (size_t)b * Tt * Hh;

  // Per-lane gate column offsets into G rows
  int goff[8];
#pragma unroll
  for (int f = 0; f < 8; ++f) {
    int ftype = f >> 1, half = f & 1;
    goff[f] = ftype * 128 + w * 32 + half * 16 + l15;
  }

  float gcur[8], gnext[8];
#pragma unroll
  for (int f = 0; f < 8; ++f) gcur[f] = Gb[goff[f]];           // t = 0
#pragma unroll
  for (int f = 0; f < 8; ++f) gnext[f] = Gb[512 + goff[f]];    // t = 1

  float c0 = 0.f, c1 = 0.f;
  int j0 = w * 32 + l15;       // unit for half 0
  // half 1 unit = j0 + 16

  for (int t = 0; t < Tt; ++t) {
    int cur = t & 1;
    // A-frags: every lane reads the same h slice (rows replicated)
    const unsigned short* hp = h_sh[cur];
    short8 af[4];
#pragma unroll
    for (int kf = 0; kf < 4; ++kf)
      af[kf] = *(const short8*)(hp + kf * 32 + quad * 8);

    floatx4 acc[8];
#pragma unroll
    for (int f = 0; f < 8; ++f)
      acc[f] = (floatx4){gcur[f], gcur[f], gcur[f], gcur[f]};
#pragma unroll
    for (int kf = 0; kf < 4; ++kf)
#pragma unroll
      for (int f = 0; f < 8; ++f)
        acc[f] = __builtin_amdgcn_mfma_f32_16x16x32_bf16(af[kf], bfr[f][kf], acc[f], 0, 0, 0);

    // rotate G prefetch (loads for t+2 overlap MFMA+nonlin latency)
#pragma unroll
    for (int f = 0; f < 8; ++f) gcur[f] = gnext[f];
    if (t + 2 < Tt) {
      const float* Gt2 = Gb + (size_t)(t + 2) * 512;
#pragma unroll
      for (int f = 0; f < 8; ++f) gnext[f] = Gt2[goff[f]];
    }

    // Nonlinearity — acc[f][0] is the gate value in every lane (rows identical)
    float ig0 = acc[0][0], ig1 = acc[1][0];
    float fg0 = acc[2][0], fg1 = acc[3][0];
    float gg0 = acc[4][0], gg1 = acc[5][0];
    float og0 = acc[6][0], og1 = acc[7][0];

    float si0 = sigmoid_fast(ig0), si1 = sigmoid_fast(ig1);
    float sf0 = sigmoid_fast(fg0), sf1 = sigmoid_fast(fg1);
    float so0 = sigmoid_fast(og0), so1 = sigmoid_fast(og1);
    float tg0 = tanh_fast(gg0),    tg1 = tanh_fast(gg1);

    c0 = sf0 * c0 + si0 * tg0;
    c1 = sf1 * c1 + si1 * tg1;
    float hv0 = so0 * tanh_fast(c0);
    float hv1 = so1 * tanh_fast(c1);

    // quads 1-3 are duplicates; quad 0 commits results
    if (quad == 0) {
      float* xo = Xeb + (size_t)t * Hh;
      xo[j0] = hv0;
      xo[j0 + 16] = hv1;
      unsigned short* hn = h_sh[cur ^ 1];
      hn[j0] = f2bf(hv0);
      hn[j0 + 16] = f2bf(hv1);
    }
    __syncthreads();
  }
}

// ---------------------------------------------------------------------------
extern "C" void kernel_launch(void* const* d_in, const int* in_sizes, int n_in,
                              void* d_out, int out_size, void* d_ws, size_t ws_size,
                              hipStream_t stream) {
  const float* X      = (const float*)d_in[0];
  const float* attn_w = (const float*)d_in[1];
  // d_in[2] = attn_b: cancels in softmax, unused
  const float* w_ih   = (const float*)d_in[3];
  const float* w_hh   = (const float*)d_in[4];
  const float* b_ih   = (const float*)d_in[5];
  const float* b_hh   = (const float*)d_in[6];

  float* Xt = (float*)d_out;                                  // (B,T,N)
  float* Xe = (float*)d_out + (size_t)Bb * Tt * Nn;           // (B,T,H)

  char* ws = (char*)d_ws;
  float*          alpha = (float*)(ws);                        //   512 KB
  float*          bias  = (float*)(ws + 524288);               //     2 KB
  unsigned short* wb    = (unsigned short*)(ws + 526336);      //   512 KB
  unsigned short* xtb   = (unsigned short*)(ws + 1050624);     //    32 MB
  float*          G     = (float*)(ws + 34605056);             //    64 MB
  // total ws use ~97 MB

  prep_kernel<<<dim3(1024), dim3(256), 0, stream>>>(w_ih, b_ih, b_hh, wb, bias);
  alpha_kernel<<<dim3(Bb), dim3(512), 0, stream>>>(X, attn_w, alpha);
  scale_kernel<<<dim3(16384), dim3(256), 0, stream>>>(X, alpha, Xt, xtb);
  gemm_bt<<<dim3(256, 4), dim3(256), 0, stream>>>(xtb, wb, bias, G);
  lstm_kernel<<<dim3(Bb), dim3(512 / 2), 0, stream>>>(G, w_hh, Xe);
}

// Round 3
// 289.980 us; speedup vs baseline: 1.1349x; 1.1174x over previous
//
#include <hip/hip_runtime.h>
#include <hip/hip_bf16.h>

// Problem constants
#define Bb 256
#define Tt 128
#define Nn 512
#define Hh 128
// 4H = 512

typedef __attribute__((ext_vector_type(4))) float floatx4;
typedef __attribute__((ext_vector_type(8))) short short8;

__device__ __forceinline__ unsigned short f2bf(float f) {
  unsigned u = __float_as_uint(f);
  u += 0x7fffu + ((u >> 16) & 1u);   // round-to-nearest-even
  return (unsigned short)(u >> 16);
}

// Fast activations: v_exp + v_rcp (~1ulp each) instead of IEEE div sequences.
__device__ __forceinline__ float sigmoid_fast(float x) {
  return __builtin_amdgcn_rcpf(1.f + __expf(-x));
}
__device__ __forceinline__ float tanh_fast(float x) {
  float e = __expf(2.f * x);                       // inf-safe
  return 1.f - 2.f * __builtin_amdgcn_rcpf(e + 1.f);
}

// Workgroup barrier that does NOT drain vmcnt: only LDS ops are waited.
// Global loads/stores issued before it stay in flight across the barrier.
__device__ __forceinline__ void lds_barrier() {
  asm volatile("s_waitcnt lgkmcnt(0)" ::: "memory");
  __builtin_amdgcn_s_barrier();
  asm volatile("" ::: "memory");
}

// ---------------------------------------------------------------------------
// Kernel 1: convert w_ih to bf16, precompute bias = b_ih + b_hh
// ---------------------------------------------------------------------------
__global__ void prep_kernel(const float* __restrict__ w_ih,
                            const float* __restrict__ b_ih,
                            const float* __restrict__ b_hh,
                            unsigned short* __restrict__ wb,
                            float* __restrict__ bias) {
  int i = blockIdx.x * 256 + threadIdx.x;
  if (i < 4 * Hh * Nn) wb[i] = f2bf(w_ih[i]);
  if (i < 4 * Hh) bias[i] = b_ih[i] + b_hh[i];
}

// ---------------------------------------------------------------------------
// Kernel 2: alpha[b,n] = softmax_n( sum_t X[b,t,n] * w_x[t] )
// (softmax shift-invariance kills the h/c-dependent scalar term)
// ---------------------------------------------------------------------------
__global__ __launch_bounds__(512) void alpha_kernel(const float* __restrict__ X,
                                                    const float* __restrict__ attn_w,
                                                    float* __restrict__ alpha) {
  int b = blockIdx.x;
  int n = threadIdx.x;                     // 512 threads
  const float* Xb = X + (size_t)b * Tt * Nn + n;
  float acc = 0.f;
#pragma unroll 8
  for (int t = 0; t < Tt; ++t)
    acc = fmaf(Xb[(size_t)t * Nn], attn_w[2 * Hh + t], acc);

  __shared__ float red[512];
  red[n] = acc;
  __syncthreads();
  for (int s = 256; s > 0; s >>= 1) {
    if (n < s) red[n] = fmaxf(red[n], red[n + s]);
    __syncthreads();
  }
  float m = red[0];
  __syncthreads();
  float e = __expf(acc - m);
  red[n] = e;
  __syncthreads();
  for (int s = 256; s > 0; s >>= 1) {
    if (n < s) red[n] += red[n + s];
    __syncthreads();
  }
  alpha[(size_t)b * Nn + n] = e / red[0];
}

// ---------------------------------------------------------------------------
// Kernel 3: Xt = alpha * X (fp32, output 0) and xtb = bf16(Xt) for the GEMM
// ---------------------------------------------------------------------------
__global__ __launch_bounds__(256) void scale_kernel(const float* __restrict__ X,
                                                    const float* __restrict__ alpha,
                                                    float* __restrict__ Xt,
                                                    unsigned short* __restrict__ xtb) {
  size_t i = (size_t)blockIdx.x * 256 + threadIdx.x;  // float4 index; grid is exact
  size_t e = i * 4;
  int n = (int)(e & (Nn - 1));
  int brow = (int)(e >> 9);   // b*T + t
  int b = brow >> 7;          // T = 128
  float4 x = ((const float4*)X)[i];
  float4 a = *(const float4*)(alpha + (size_t)b * Nn + n);
  float4 y;
  y.x = x.x * a.x; y.y = x.y * a.y; y.z = x.z * a.z; y.w = x.w * a.w;
  ((float4*)Xt)[i] = y;
  ushort4 u;
  u.x = f2bf(y.x); u.y = f2bf(y.y); u.z = f2bf(y.z); u.w = f2bf(y.w);
  ((ushort4*)xtb)[i] = u;
}

// ---------------------------------------------------------------------------
// Kernel 4: G[m, j] = sum_k xtb[m,k] * w_ih[j,k] + bias[j]   (bf16 MFMA)
// M = B*T = 32768, N = 512, K = 512. B^T layout (w_ih rows are k-contiguous).
// 128x128 block tile, 4 waves in 2x2, each wave 64x64 via 4x4 frags 16x16x32.
// ---------------------------------------------------------------------------
#define GBK 64
#define LDK 72  // GBK + 8 bf16 pad -> 144B row stride, 2-way-max bank aliasing

__global__ __launch_bounds__(256) void gemm_bt(const unsigned short* __restrict__ A,
                                               const unsigned short* __restrict__ Bw,
                                               const float* __restrict__ bias,
                                               float* __restrict__ C) {
  __shared__ __align__(16) unsigned short As[128 * LDK];
  __shared__ __align__(16) unsigned short Bs[128 * LDK];
  const int K = 512, NO = 512;
  int tid = threadIdx.x;
  int lane = tid & 63;
  int wave = tid >> 6;
  int wm = wave & 1, wn = wave >> 1;
  int l15 = lane & 15;
  int quad = lane >> 4;
  int mtile = blockIdx.x, ntile = blockIdx.y;

  floatx4 acc[4][4];
#pragma unroll
  for (int i = 0; i < 4; ++i)
#pragma unroll
    for (int j = 0; j < 4; ++j) acc[i][j] = (floatx4){0.f, 0.f, 0.f, 0.f};

  const size_t abase = (size_t)mtile * 128 * K;
  const size_t bbase = (size_t)ntile * 128 * K;

  for (int kb = 0; kb < K; kb += GBK) {
    // stage 128x64 bf16 tiles of A and B^T; 16B per thread per slot
#pragma unroll
    for (int s = 0; s < 4; ++s) {
      int idx = s * 256 + tid;       // 0..1023
      int r = idx >> 3;
      int c = (idx & 7) * 8;
      uint4 va = *(const uint4*)(A + abase + (size_t)r * K + kb + c);
      *(uint4*)(&As[r * LDK + c]) = va;
      uint4 vb = *(const uint4*)(Bw + bbase + (size_t)r * K + kb + c);
      *(uint4*)(&Bs[r * LDK + c]) = vb;
    }
    __syncthreads();
#pragma unroll
    for (int ks = 0; ks < GBK; ks += 32) {
      int kof = ks + quad * 8;
      short8 af[4], bf[4];
#pragma unroll
      for (int i = 0; i < 4; ++i)
        af[i] = *(const short8*)(&As[(wm * 64 + i * 16 + l15) * LDK + kof]);
#pragma unroll
      for (int j = 0; j < 4; ++j)
        bf[j] = *(const short8*)(&Bs[(wn * 64 + j * 16 + l15) * LDK + kof]);
#pragma unroll
      for (int i = 0; i < 4; ++i)
#pragma unroll
        for (int j = 0; j < 4; ++j)
          acc[i][j] = __builtin_amdgcn_mfma_f32_16x16x32_bf16(af[i], bf[j], acc[i][j], 0, 0, 0);
    }
    __syncthreads();
  }

  // Epilogue: C/D mapping col = lane&15 (n), row = quad*4 + reg (m)
  int m0 = mtile * 128 + wm * 64;
  int n0 = ntile * 128 + wn * 64;
#pragma unroll
  for (int j = 0; j < 4; ++j) {
    int col = n0 + j * 16 + l15;
    float bsum = bias[col];
#pragma unroll
    for (int i = 0; i < 4; ++i) {
      int row = m0 + i * 16 + quad * 4;
#pragma unroll
      for (int r = 0; r < 4; ++r)
        C[(size_t)(row + r) * NO + col] = acc[i][j][r] + bsum;
    }
  }
}

// ---------------------------------------------------------------------------
// Kernel 5: sequential LSTM via M-replicated MFMA.
// One block per batch, 256 threads = 4 waves. Each wave owns 8 n-frags:
//   n(f) = ftype*128 + wave*32 + half*16   (f = ftype*2 + half)
// so i,f,g,o for unit j = wave*32 + half*16 + l15 all live in the SAME lane.
// A-operand: every lane loads the same h[k] slice -> all 16 M-rows identical
// -> acc[f][0] is a valid gate in EVERY lane (quads are natural duplicates).
// G_t enters as the MFMA C-operand (splat), prefetched 2 steps ahead.
// T-loop uses lds_barrier() (lgkmcnt-only) so the G prefetch loads and Xe
// stores are NOT drained at each step's barrier (the vmcnt(0)-before-
// s_barrier drain was the R2 bottleneck: ~900 cyc/step of exposed latency).
// ---------------------------------------------------------------------------
__global__ __launch_bounds__(256, 1) void lstm_kernel(const float* __restrict__ G,
                                                      const float* __restrict__ w_hh,
                                                      float* __restrict__ Xe) {
  int b = blockIdx.x;
  int tid = threadIdx.x;
  int w = tid >> 6;
  int lane = tid & 63;
  int l15 = lane & 15;
  int quad = lane >> 4;

  // Preload w_hh^T B-frags (bf16). B-frag layout: n = l15, k = quad*8 + jj
  short8 bfr[8][4];
#pragma unroll
  for (int f = 0; f < 8; ++f) {
    int ftype = f >> 1, half = f & 1;
    int n = ftype * 128 + w * 32 + half * 16 + l15;
    const float* src = w_hh + (size_t)n * 128;
#pragma unroll
    for (int kf = 0; kf < 4; ++kf) {
      int k0 = kf * 32 + quad * 8;
      float4 lo = *(const float4*)(src + k0);
      float4 hi = *(const float4*)(src + k0 + 4);
      short8 v;
      v[0] = (short)f2bf(lo.x); v[1] = (short)f2bf(lo.y);
      v[2] = (short)f2bf(lo.z); v[3] = (short)f2bf(lo.w);
      v[4] = (short)f2bf(hi.x); v[5] = (short)f2bf(hi.y);
      v[6] = (short)f2bf(hi.z); v[7] = (short)f2bf(hi.w);
      bfr[f][kf] = v;
    }
  }

  __shared__ __align__(16) unsigned short h_sh[2][128];
  if (tid < 128) h_sh[0][tid] = 0;   // h0 = 0 (bf16 zero)
  __syncthreads();

  const float* Gb = G + (size_t)b * Tt * 512;
  float* Xeb = Xe + (size_t)b * Tt * Hh;

  // Per-lane gate column offsets into G rows
  int goff[8];
#pragma unroll
  for (int f = 0; f < 8; ++f) {
    int ftype = f >> 1, half = f & 1;
    goff[f] = ftype * 128 + w * 32 + half * 16 + l15;
  }

  float gcur[8], gnext[8];
#pragma unroll
  for (int f = 0; f < 8; ++f) gcur[f] = Gb[goff[f]];           // t = 0
#pragma unroll
  for (int f = 0; f < 8; ++f) gnext[f] = Gb[512 + goff[f]];    // t = 1

  float c0 = 0.f, c1 = 0.f;
  int j0 = w * 32 + l15;       // unit for half 0; half-1 unit = j0 + 16

  for (int t = 0; t < Tt; ++t) {
    int cur = t & 1;
    // A-frags: every lane reads the same h slice (rows replicated; broadcast)
    const unsigned short* hp = h_sh[cur];
    short8 af[4];
#pragma unroll
    for (int kf = 0; kf < 4; ++kf)
      af[kf] = *(const short8*)(hp + kf * 32 + quad * 8);

    floatx4 acc[8];
#pragma unroll
    for (int f = 0; f < 8; ++f)
      acc[f] = (floatx4){gcur[f], gcur[f], gcur[f], gcur[f]};

    // rotate + issue next prefetch EARLY so the loads overlap MFMA + nonlin
#pragma unroll
    for (int f = 0; f < 8; ++f) gcur[f] = gnext[f];
    if (t + 2 < Tt) {
      const float* Gt2 = Gb + (size_t)(t + 2) * 512;
#pragma unroll
      for (int f = 0; f < 8; ++f) gnext[f] = Gt2[goff[f]];
    }

#pragma unroll
    for (int kf = 0; kf < 4; ++kf)
#pragma unroll
      for (int f = 0; f < 8; ++f)
        acc[f] = __builtin_amdgcn_mfma_f32_16x16x32_bf16(af[kf], bfr[f][kf], acc[f], 0, 0, 0);

    // Nonlinearity — acc[f][0] is the gate value in every lane (rows identical)
    float si0 = sigmoid_fast(acc[0][0]), si1 = sigmoid_fast(acc[1][0]);
    float sf0 = sigmoid_fast(acc[2][0]), sf1 = sigmoid_fast(acc[3][0]);
    float tg0 = tanh_fast(acc[4][0]),    tg1 = tanh_fast(acc[5][0]);
    float so0 = sigmoid_fast(acc[6][0]), so1 = sigmoid_fast(acc[7][0]);

    c0 = sf0 * c0 + si0 * tg0;
    c1 = sf1 * c1 + si1 * tg1;
    float hv0 = so0 * tanh_fast(c0);
    float hv1 = so1 * tanh_fast(c1);

    // quads 1-3 are duplicates; quad 0 commits results
    if (quad == 0) {
      float* xo = Xeb + (size_t)t * Hh;
      xo[j0] = hv0;
      xo[j0 + 16] = hv1;
      unsigned short* hn = h_sh[cur ^ 1];
      hn[j0] = f2bf(hv0);
      hn[j0 + 16] = f2bf(hv1);
    }
    lds_barrier();   // LDS-only drain; G loads / Xe stores stay in flight
  }
}

// ---------------------------------------------------------------------------
extern "C" void kernel_launch(void* const* d_in, const int* in_sizes, int n_in,
                              void* d_out, int out_size, void* d_ws, size_t ws_size,
                              hipStream_t stream) {
  const float* X      = (const float*)d_in[0];
  const float* attn_w = (const float*)d_in[1];
  // d_in[2] = attn_b: cancels in softmax, unused
  const float* w_ih   = (const float*)d_in[3];
  const float* w_hh   = (const float*)d_in[4];
  const float* b_ih   = (const float*)d_in[5];
  const float* b_hh   = (const float*)d_in[6];

  float* Xt = (float*)d_out;                                  // (B,T,N)
  float* Xe = (float*)d_out + (size_t)Bb * Tt * Nn;           // (B,T,H)

  char* ws = (char*)d_ws;
  float*          alpha = (float*)(ws);                        //   512 KB
  float*          bias  = (float*)(ws + 524288);               //     2 KB
  unsigned short* wb    = (unsigned short*)(ws + 526336);      //   512 KB
  unsigned short* xtb   = (unsigned short*)(ws + 1050624);     //    32 MB
  float*          G     = (float*)(ws + 34605056);             //    64 MB
  // total ws use ~97 MB

  prep_kernel<<<dim3(1024), dim3(256), 0, stream>>>(w_ih, b_ih, b_hh, wb, bias);
  alpha_kernel<<<dim3(Bb), dim3(512), 0, stream>>>(X, attn_w, alpha);
  scale_kernel<<<dim3(16384), dim3(256), 0, stream>>>(X, alpha, Xt, xtb);
  gemm_bt<<<dim3(256, 4), dim3(256), 0, stream>>>(xtb, wb, bias, G);
  lstm_kernel<<<dim3(Bb), dim3(512 / 2), 0, stream>>>(G, w_hh, Xe);
}

// Round 4
// 275.064 us; speedup vs baseline: 1.1964x; 1.0542x over previous
//
#include <hip/hip_runtime.h>
#include <hip/hip_bf16.h>

// Problem constants
#define Bb 256
#define Tt 128
#define Nn 512
#define Hh 128
// 4H = 512

typedef __attribute__((ext_vector_type(4))) float floatx4;
typedef __attribute__((ext_vector_type(8))) short short8;

__device__ __forceinline__ unsigned short f2bf(float f) {
  unsigned u = __float_as_uint(f);
  u += 0x7fffu + ((u >> 16) & 1u);   // round-to-nearest-even
  return (unsigned short)(u >> 16);
}

// Fast activations: v_exp + v_rcp (~1ulp each) instead of IEEE div sequences.
__device__ __forceinline__ float sigmoid_fast(float x) {
  return __builtin_amdgcn_rcpf(1.f + __expf(-x));
}
__device__ __forceinline__ float tanh_fast(float x) {
  float e = __expf(2.f * x);                       // inf-safe
  return 1.f - 2.f * __builtin_amdgcn_rcpf(e + 1.f);
}

// Workgroup barrier that does NOT drain vmcnt: only LDS ops are waited.
// Global loads/stores issued before it stay in flight across the barrier.
__device__ __forceinline__ void lds_barrier() {
  asm volatile("s_waitcnt lgkmcnt(0)" ::: "memory");
  __builtin_amdgcn_s_barrier();
  asm volatile("" ::: "memory");
}

__device__ __forceinline__ void async_load16(const void* g, void* lds) {
  __builtin_amdgcn_global_load_lds(
      (const __attribute__((address_space(1))) unsigned int*)g,
      (__attribute__((address_space(3))) unsigned int*)lds, 16, 0, 0);
}

// ---------------------------------------------------------------------------
// Kernel 1: convert w_ih to bf16, precompute bias = b_ih + b_hh
// ---------------------------------------------------------------------------
__global__ void prep_kernel(const float* __restrict__ w_ih,
                            const float* __restrict__ b_ih,
                            const float* __restrict__ b_hh,
                            unsigned short* __restrict__ wb,
                            float* __restrict__ bias) {
  int i = blockIdx.x * 256 + threadIdx.x;
  if (i < 4 * Hh * Nn) wb[i] = f2bf(w_ih[i]);
  if (i < 4 * Hh) bias[i] = b_ih[i] + b_hh[i];
}

// ---------------------------------------------------------------------------
// Kernel 2: alpha[b,n] = softmax_n( sum_t X[b,t,n] * w_x[t] )
// (softmax shift-invariance kills the h/c-dependent scalar term)
// ---------------------------------------------------------------------------
__global__ __launch_bounds__(512) void alpha_kernel(const float* __restrict__ X,
                                                    const float* __restrict__ attn_w,
                                                    float* __restrict__ alpha) {
  int b = blockIdx.x;
  int n = threadIdx.x;                     // 512 threads
  const float* Xb = X + (size_t)b * Tt * Nn + n;
  float acc = 0.f;
#pragma unroll 8
  for (int t = 0; t < Tt; ++t)
    acc = fmaf(Xb[(size_t)t * Nn], attn_w[2 * Hh + t], acc);

  __shared__ float red[512];
  red[n] = acc;
  __syncthreads();
  for (int s = 256; s > 0; s >>= 1) {
    if (n < s) red[n] = fmaxf(red[n], red[n + s]);
    __syncthreads();
  }
  float m = red[0];
  __syncthreads();
  float e = __expf(acc - m);
  red[n] = e;
  __syncthreads();
  for (int s = 256; s > 0; s >>= 1) {
    if (n < s) red[n] += red[n + s];
    __syncthreads();
  }
  alpha[(size_t)b * Nn + n] = e / red[0];
}

// ---------------------------------------------------------------------------
// Kernel 3: Xt = alpha * X (fp32, output 0) and xtb = bf16(Xt) for the GEMM
// ---------------------------------------------------------------------------
__global__ __launch_bounds__(256) void scale_kernel(const float* __restrict__ X,
                                                    const float* __restrict__ alpha,
                                                    float* __restrict__ Xt,
                                                    unsigned short* __restrict__ xtb) {
  size_t i = (size_t)blockIdx.x * 256 + threadIdx.x;  // float4 index; grid is exact
  size_t e = i * 4;
  int n = (int)(e & (Nn - 1));
  int brow = (int)(e >> 9);   // b*T + t
  int b = brow >> 7;          // T = 128
  float4 x = ((const float4*)X)[i];
  float4 a = *(const float4*)(alpha + (size_t)b * Nn + n);
  float4 y;
  y.x = x.x * a.x; y.y = x.y * a.y; y.z = x.z * a.z; y.w = x.w * a.w;
  ((float4*)Xt)[i] = y;
  ushort4 u;
  u.x = f2bf(y.x); u.y = f2bf(y.y); u.z = f2bf(y.z); u.w = f2bf(y.w);
  ((ushort4*)xtb)[i] = u;
}

// ---------------------------------------------------------------------------
// Kernel 4: G[m, j] = sum_k xtb[m,k] * w_ih[j,k] + bias[j]   (bf16 MFMA)
// M = B*T = 32768, N = 512, K = 512. B^T layout (w_ih rows are k-contiguous).
// 128x128 block tile, 4 waves 2x2, 64x64/wave via 4x4 frags of 16x16x32.
// Staging via global_load_lds (16B) into XOR-swizzled LDS:
//   LDS chunk s (16B) of row r holds global k-chunk  s ^ (r & 7).
// Wave-slot: wave w stages rows r0 = slot*32 + w*8 (1024 B contiguous LDS);
// lane l -> row r0 + (l>>3), LDS chunk l&7, so global chunk (l&7)^(l>>3).
// MFMA reads row (…+l15), k-chunk (quad + 4*kh): LDS chunk = that ^ (l15&7)
// -> 2 lanes/bank max (free per m136). No pad, 16 KB per array.
// ---------------------------------------------------------------------------
#define GBK 64

__global__ __launch_bounds__(256) void gemm_bt(const unsigned short* __restrict__ A,
                                               const unsigned short* __restrict__ Bw,
                                               const float* __restrict__ bias,
                                               float* __restrict__ C) {
  __shared__ __align__(16) unsigned short As[128 * 64];
  __shared__ __align__(16) unsigned short Bs[128 * 64];
  const int K = 512, NO = 512;
  int tid = threadIdx.x;
  int lane = tid & 63;
  int wave = tid >> 6;
  int wm = wave & 1, wn = wave >> 1;
  int l15 = lane & 15;
  int quad = lane >> 4;
  int mtile = blockIdx.x, ntile = blockIdx.y;

  floatx4 acc[4][4];
#pragma unroll
  for (int i = 0; i < 4; ++i)
#pragma unroll
    for (int j = 0; j < 4; ++j) acc[i][j] = (floatx4){0.f, 0.f, 0.f, 0.f};

  // staging addresses
  int lr = lane >> 3;                 // local row within wave-slot (0..7)
  int lc = (lane & 7) ^ lr;           // swizzled global k-chunk for this lane
  const size_t lane_goff = (size_t)lr * K + lc * 8;
  const size_t abase = (size_t)mtile * 128 * K + lane_goff;
  const size_t bbase = (size_t)ntile * 128 * K + lane_goff;
  // MFMA read swizzle (lane-static)
  int sw = (quad ^ (l15 & 7)) * 8;    // element offset of chunk for kh=0

  for (int kb = 0; kb < K; kb += GBK) {
#pragma unroll
    for (int slot = 0; slot < 4; ++slot) {
      int r0 = slot * 32 + wave * 8;
      async_load16(A + abase + (size_t)r0 * K + kb, &As[r0 * 64]);
      async_load16(Bw + bbase + (size_t)r0 * K + kb, &Bs[r0 * 64]);
    }
    __syncthreads();   // drains vmcnt(0): LDS-DMA complete
#pragma unroll
    for (int kh = 0; kh < 2; ++kh) {
      int sc = sw ^ (kh * 32);        // ^ (4 chunks * 8 elem)
      short8 af[4], bf[4];
#pragma unroll
      for (int i = 0; i < 4; ++i)
        af[i] = *(const short8*)(&As[(wm * 64 + i * 16 + l15) * 64 + sc]);
#pragma unroll
      for (int j = 0; j < 4; ++j)
        bf[j] = *(const short8*)(&Bs[(wn * 64 + j * 16 + l15) * 64 + sc]);
#pragma unroll
      for (int i = 0; i < 4; ++i)
#pragma unroll
        for (int j = 0; j < 4; ++j)
          acc[i][j] = __builtin_amdgcn_mfma_f32_16x16x32_bf16(af[i], bf[j], acc[i][j], 0, 0, 0);
    }
    __syncthreads();
  }

  // Epilogue: C/D mapping col = lane&15 (n), row = quad*4 + reg (m)
  int m0 = mtile * 128 + wm * 64;
  int n0 = ntile * 128 + wn * 64;
#pragma unroll
  for (int j = 0; j < 4; ++j) {
    int col = n0 + j * 16 + l15;
    float bsum = bias[col];
#pragma unroll
    for (int i = 0; i < 4; ++i) {
      int row = m0 + i * 16 + quad * 4;
#pragma unroll
      for (int r = 0; r < 4; ++r)
        C[(size_t)(row + r) * NO + col] = acc[i][j][r] + bsum;
    }
  }
}

// ---------------------------------------------------------------------------
// Kernel 5: sequential LSTM via M-replicated MFMA, 8 waves (512 thr)/batch.
// Wave w owns units j = w*16 + l15; frag f = gate type (i,f,g,o) at
// col = f*128 + w*16 + l15. Per step per wave: 16 MFMA (4 frags x 4 k-frags)
// -> 2 waves/SIMD so MFMA pipe time (620 cyc/SIMD/step, the R3 floor)
// overlaps the other wave's VALU nonlinearity. acc[f][0] is the gate value
// in every lane (A rows = replicated h). lgkmcnt-only barrier per step.
// ---------------------------------------------------------------------------
__global__ __launch_bounds__(512, 1) void lstm_kernel(const float* __restrict__ G,
                                                      const float* __restrict__ w_hh,
                                                      float* __restrict__ Xe) {
  int b = blockIdx.x;
  int tid = threadIdx.x;
  int w = tid >> 6;          // 8 waves
  int lane = tid & 63;
  int l15 = lane & 15;
  int quad = lane >> 4;

  // Preload w_hh B-frags (bf16). B-frag layout: n = l15, k = quad*8 + jj
  short8 bfr[4][4];
#pragma unroll
  for (int f = 0; f < 4; ++f) {
    int n = f * 128 + w * 16 + l15;
    const float* src = w_hh + (size_t)n * 128;
#pragma unroll
    for (int kf = 0; kf < 4; ++kf) {
      int k0 = kf * 32 + quad * 8;
      float4 lo = *(const float4*)(src + k0);
      float4 hi = *(const float4*)(src + k0 + 4);
      short8 v;
      v[0] = (short)f2bf(lo.x); v[1] = (short)f2bf(lo.y);
      v[2] = (short)f2bf(lo.z); v[3] = (short)f2bf(lo.w);
      v[4] = (short)f2bf(hi.x); v[5] = (short)f2bf(hi.y);
      v[6] = (short)f2bf(hi.z); v[7] = (short)f2bf(hi.w);
      bfr[f][kf] = v;
    }
  }

  __shared__ __align__(16) unsigned short h_sh[2][128];
  if (tid < 128) h_sh[0][tid] = 0;   // h0 = 0 (bf16 zero)
  __syncthreads();

  const float* Gb = G + (size_t)b * Tt * 512;
  float* Xeb = Xe + (size_t)b * Tt * Hh;

  // Per-lane gate column offsets into G rows
  int goff[4];
#pragma unroll
  for (int f = 0; f < 4; ++f) goff[f] = f * 128 + w * 16 + l15;

  float gcur[4], gnext[4];
#pragma unroll
  for (int f = 0; f < 4; ++f) gcur[f] = Gb[goff[f]];           // t = 0
#pragma unroll
  for (int f = 0; f < 4; ++f) gnext[f] = Gb[512 + goff[f]];    // t = 1

  float c0 = 0.f;
  int j0 = w * 16 + l15;     // this lane's unit

  for (int t = 0; t < Tt; ++t) {
    int cur = t & 1;
    // A-frags: every lane reads the same h slice (rows replicated; broadcast)
    const unsigned short* hp = h_sh[cur];
    short8 af[4];
#pragma unroll
    for (int kf = 0; kf < 4; ++kf)
      af[kf] = *(const short8*)(hp + kf * 32 + quad * 8);

    floatx4 acc[4];
#pragma unroll
    for (int f = 0; f < 4; ++f)
      acc[f] = (floatx4){gcur[f], gcur[f], gcur[f], gcur[f]};

    // rotate + issue next prefetch EARLY so the loads overlap MFMA + nonlin
#pragma unroll
    for (int f = 0; f < 4; ++f) gcur[f] = gnext[f];
    if (t + 2 < Tt) {
      const float* Gt2 = Gb + (size_t)(t + 2) * 512;
#pragma unroll
      for (int f = 0; f < 4; ++f) gnext[f] = Gt2[goff[f]];
    }

#pragma unroll
    for (int kf = 0; kf < 4; ++kf)
#pragma unroll
      for (int f = 0; f < 4; ++f)
        acc[f] = __builtin_amdgcn_mfma_f32_16x16x32_bf16(af[kf], bfr[f][kf], acc[f], 0, 0, 0);

    // Nonlinearity — acc[f][0] is the gate value in every lane (rows identical)
    float si = sigmoid_fast(acc[0][0]);
    float sf = sigmoid_fast(acc[1][0]);
    float tg = tanh_fast(acc[2][0]);
    float so = sigmoid_fast(acc[3][0]);

    c0 = sf * c0 + si * tg;
    float hv = so * tanh_fast(c0);

    // quads 1-3 are duplicates; quad 0 commits results
    if (quad == 0) {
      Xeb[(size_t)t * Hh + j0] = hv;
      h_sh[cur ^ 1][j0] = f2bf(hv);
    }
    lds_barrier();   // LDS-only drain; G loads / Xe stores stay in flight
  }
}

// ---------------------------------------------------------------------------
extern "C" void kernel_launch(void* const* d_in, const int* in_sizes, int n_in,
                              void* d_out, int out_size, void* d_ws, size_t ws_size,
                              hipStream_t stream) {
  const float* X      = (const float*)d_in[0];
  const float* attn_w = (const float*)d_in[1];
  // d_in[2] = attn_b: cancels in softmax, unused
  const float* w_ih   = (const float*)d_in[3];
  const float* w_hh   = (const float*)d_in[4];
  const float* b_ih   = (const float*)d_in[5];
  const float* b_hh   = (const float*)d_in[6];

  float* Xt = (float*)d_out;                                  // (B,T,N)
  float* Xe = (float*)d_out + (size_t)Bb * Tt * Nn;           // (B,T,H)

  char* ws = (char*)d_ws;
  float*          alpha = (float*)(ws);                        //   512 KB
  float*          bias  = (float*)(ws + 524288);               //     2 KB
  unsigned short* wb    = (unsigned short*)(ws + 526336);      //   512 KB
  unsigned short* xtb   = (unsigned short*)(ws + 1050624);     //    32 MB
  float*          G     = (float*)(ws + 34605056);             //    64 MB
  // total ws use ~97 MB

  prep_kernel<<<dim3(1024), dim3(256), 0, stream>>>(w_ih, b_ih, b_hh, wb, bias);
  alpha_kernel<<<dim3(Bb), dim3(512), 0, stream>>>(X, attn_w, alpha);
  scale_kernel<<<dim3(16384), dim3(256), 0, stream>>>(X, alpha, Xt, xtb);
  gemm_bt<<<dim3(256, 4), dim3(256), 0, stream>>>(xtb, wb, bias, G);
  lstm_kernel<<<dim3(Bb), dim3(512), 0, stream>>>(G, w_hh, Xe);
}